// Round 20
// baseline (159.944 us; speedup 1.0000x reference)
//
#include <hip/hip_runtime.h>
#include <hip/hip_bf16.h>

#define B_ 2
#define C_ 256
#define S_ 4096
#define NH 8
#define HD 32
#define EPSV 1e-5f
// QSCALE * log2(e): scores computed in log2 units so softmax uses exp2
#define QSC2 0.25503487942324256f

typedef __bf16 bf16_t;
typedef bf16_t bf16x8 __attribute__((ext_vector_type(8)));
typedef float f32x4 __attribute__((ext_vector_type(4)));
typedef float f32x16 __attribute__((ext_vector_type(16)));
typedef int i32x2 __attribute__((ext_vector_type(2)));
typedef __hip_bfloat16 hbf;

__device__ inline unsigned cvtpk_bf16(float a, float b) {
  unsigned r;
  asm("v_cvt_pk_bf16_f32 %0, %1, %2" : "=v"(r) : "v"(a), "v"(b));
  return r;
}

// raw hardware exp2 (v_exp_f32): scores are tiny, no range handling needed
#if __has_builtin(__builtin_amdgcn_exp2f)
#define EXP2R(x) __builtin_amdgcn_exp2f(x)
#else
#define EXP2R(x) exp2f(x)
#endif

// ---------------- fused weights + groupnorm (stats -> barrier -> apply), ONE kernel ----------------
// blocks [0,96): qkv_w -> fragment-major; [96,128): proj_w -> fragment-major;
// [128,640): gn: per-chunk partial sums -> device-scope arrive (cnt[bg]) -> spin until all 8
// chunks of the group arrived -> deterministic fixed-order total -> normalize + frag-major store.
// All 640 blocks (256 thr) co-resident trivially; spin is among 8 sibling blocks only.
__global__ __launch_bounds__(256) void gnw_fused(const float* __restrict__ qkv_w,
                                                 const float* __restrict__ proj_w,
                                                 const float* __restrict__ x,
                                                 const float* __restrict__ gn_w,
                                                 const float* __restrict__ gn_b,
                                                 hbf* __restrict__ qkv_wf, hbf* __restrict__ proj_wf,
                                                 float* __restrict__ stats, int* __restrict__ cnt,
                                                 hbf* __restrict__ xn) {
  int blk = blockIdx.x;
  int tid = threadIdx.x;
  if (blk < 128) {
    // weight conversion, fragment-major: wf[o/32][c/16][o%32][16]
    const float* src = (blk < 96) ? qkv_w : proj_w;
    hbf* dst = (blk < 96) ? qkv_wf : proj_wf;
    int i = (blk < 96 ? blk : blk - 96) * 256 + tid;
    int o = i >> 5, c8 = (i & 31) * 8;
    alignas(16) hbf tmp[8];
#pragma unroll
    for (int j = 0; j < 8; j++) tmp[j] = __float2bfloat16(src[(size_t)o * C_ + c8 + j]);
    *(uint4*)&dst[(((size_t)(o >> 5) * 16) + (c8 >> 4)) * 512 + (o & 31) * 16 + (c8 & 15)] = *(uint4*)tmp;
    return;
  }
  // ---- gn: 512 blocks = 64 (b,g) x 8 chunks of 512 s ----
  int sb = blk - 128;
  int bg = sb >> 3, chunk = sb & 7;
  int b = bg >> 5, g = bg & 31;
  const float* xp = x + (size_t)bg * 8 * S_;
  const float4* xp4 = (const float4*)xp;
  float sum = 0.f, sumsq = 0.f;
#pragma unroll
  for (int p = 0; p < 4; p++) {
    int i = tid + p * 256;                    // 1024 float4s: 8 ch x 128
    int ch = i >> 7, s4 = i & 127;
    float4 v = xp4[ch * (S_ >> 2) + chunk * 128 + s4];
    sum += v.x + v.y + v.z + v.w;
    sumsq += v.x * v.x + v.y * v.y + v.z * v.z + v.w * v.w;
  }
#pragma unroll
  for (int off = 32; off > 0; off >>= 1) {
    sum += __shfl_down(sum, off);
    sumsq += __shfl_down(sumsq, off);
  }
  __shared__ float red[2][4];
  __shared__ float bc[2];
  int wid = tid >> 6;
  if ((tid & 63) == 0) { red[0][wid] = sum; red[1][wid] = sumsq; }
  __syncthreads();
  if (tid == 0) {
    // publish this chunk's partials, arrive, spin for siblings, then fixed-order total
    stats[sb * 2 + 0] = red[0][0] + red[0][1] + red[0][2] + red[0][3];
    stats[sb * 2 + 1] = red[1][0] + red[1][1] + red[1][2] + red[1][3];
    __threadfence();
    __hip_atomic_fetch_add(&cnt[bg], 1, __ATOMIC_ACQ_REL, __HIP_MEMORY_SCOPE_AGENT);
    while (__hip_atomic_load(&cnt[bg], __ATOMIC_ACQUIRE, __HIP_MEMORY_SCOPE_AGENT) < 8)
      __builtin_amdgcn_s_sleep(2);
    float ts = 0.f, tq = 0.f;
#pragma unroll
    for (int k = 0; k < 8; k++) {             // fixed order: deterministic
      ts += __hip_atomic_load(&stats[(bg * 8 + k) * 2 + 0], __ATOMIC_ACQUIRE, __HIP_MEMORY_SCOPE_AGENT);
      tq += __hip_atomic_load(&stats[(bg * 8 + k) * 2 + 1], __ATOMIC_ACQUIRE, __HIP_MEMORY_SCOPE_AGENT);
    }
    const float inv_n = 1.f / (8 * S_);
    float mean = ts * inv_n;
    bc[0] = mean;
    bc[1] = rsqrtf(fmaxf(tq * inv_n - mean * mean, 0.f) + EPSV);
  }
  __syncthreads();
  float mean = bc[0], rstd = bc[1];
  float scv[8], shv[8];
#pragma unroll
  for (int c = 0; c < 8; c++) {
    scv[c] = gn_w[g * 8 + c] * rstd;
    shv[c] = gn_b[g * 8 + c] - mean * scv[c];
  }
#pragma unroll
  for (int p = 0; p < 2; p++) {
    int s = chunk * 512 + p * 256 + tid;
    alignas(16) hbf tmp[8];
#pragma unroll
    for (int c = 0; c < 8; c++)
      tmp[c] = __float2bfloat16(xp[(size_t)c * S_ + s] * scv[c] + shv[c]);
    *(uint4*)&xn[(((size_t)b * (S_ >> 5) + (s >> 5)) * 16 + (g >> 1)) * 512 + (s & 31) * 16 + (g & 1) * 8] =
        *(uint4*)tmp;
  }
}

// ---------------- QKV GEMM v2: LDS-free, fragment-major A and B ----------------
__global__ __launch_bounds__(512, 4) void qkv_gemm(const hbf* __restrict__ xn, const hbf* __restrict__ wf,
                                                   const float* __restrict__ bias,
                                                   hbf* __restrict__ qbuf, hbf* __restrict__ kg,
                                                   hbf* __restrict__ vg) {
  int bt = blockIdx.z;
  int m0 = blockIdx.x * 128;          // s-base within batch
  int n0 = blockIdx.y * 128;          // o-base
  int tid = threadIdx.x, lane = tid & 63, w = tid >> 6;
  int wq = w & 3, wo = w >> 2;
  int l31 = lane & 31, hi = lane >> 5;
  const int loff = l31 * 16 + hi * 8;
  const hbf* ap = xn + ((size_t)bt * (S_ >> 5) + (m0 >> 5) + wq) * 8192;
  int oc0 = n0 + wo * 64;
  const hbf* bp0 = wf + (size_t)(oc0 >> 5) * 8192;
  const hbf* bp1 = bp0 + 8192;
  f32x16 acc0 = {0.f,0.f,0.f,0.f,0.f,0.f,0.f,0.f,0.f,0.f,0.f,0.f,0.f,0.f,0.f,0.f};
  f32x16 acc1 = acc0;
#pragma unroll 4
  for (int ks = 0; ks < 16; ++ks) {
    bf16x8 af = *(const bf16x8*)(ap + ks * 512 + loff);
    bf16x8 b0 = *(const bf16x8*)(bp0 + ks * 512 + loff);
    bf16x8 b1 = *(const bf16x8*)(bp1 + ks * 512 + loff);
    acc0 = __builtin_amdgcn_mfma_f32_32x32x16_bf16(af, b0, acc0, 0, 0, 0);
    acc1 = __builtin_amdgcn_mfma_f32_32x32x16_bf16(af, b1, acc1, 0, 0, 0);
  }
  int s_base = m0 + wq * 32;
#pragma unroll
  for (int ct = 0; ct < 2; ++ct) {
    f32x16 a = ct ? acc1 : acc0;
    int oc = oc0 + ct * 32;           // uniform per col-tile
    int o = oc + l31;
    float bs = bias[o];
    if (oc < 256) {
#pragma unroll
      for (int r = 0; r < 16; r++) {
        int s = s_base + (r & 3) + 8 * (r >> 2) + 4 * hi;
        qbuf[((size_t)bt * S_ + s) * C_ + o] = __float2bfloat16((a[r] + bs) * QSC2);
      }
    } else if (oc < 512) {
      int hh = (oc - 256) >> 5;
      const size_t khead = (size_t)(bt * NH + hh) * (S_ >> 5);
#pragma unroll
      for (int r = 0; r < 16; r++) {
        int s = s_base + (r & 3) + 8 * (r >> 2) + 4 * hi;
        kg[(khead + (s >> 5)) * 1024 + (l31 >> 4) * 512 + (s & 31) * 16 + (l31 & 15)] =
            __float2bfloat16(a[r] + bs);
      }
    } else {
      int hh = (oc - 512) >> 5;
      const size_t vhead = (size_t)(bt * NH + hh) * (S_ >> 4);
#pragma unroll
      for (int r = 0; r < 16; r++) {
        int s = s_base + (r & 3) + 8 * (r >> 2) + 4 * hi;
        vg[(vhead + (s >> 4)) * 512 + l31 * 16 + (s & 15)] = __float2bfloat16(a[r] + bs);
      }
    }
  }
}

// softmax numerator + P relayout + PV for ONE 32-t tile (consumes sc of that tile)
// l via VALU tree (measured best split: r18 showed ones-MFMA overloads the MFMA pipe)
__device__ inline void softmax_pv(f32x16 sc, bf16x8 va0, bf16x8 va1,
                                  f32x16& o_acc, float& l_run) {
#pragma unroll
  for (int i = 0; i < 16; i++) sc[i] = EXP2R(sc[i]);
  {
    float s0a = sc[0] + sc[1], s1a = sc[2] + sc[3], s2a = sc[4] + sc[5], s3a = sc[6] + sc[7];
    float s4a = sc[8] + sc[9], s5a = sc[10] + sc[11], s6a = sc[12] + sc[13], s7a = sc[14] + sc[15];
    s0a += s1a; s2a += s3a; s4a += s5a; s6a += s7a;
    s0a += s2a; s4a += s6a;
    l_run += s0a + s4a;
  }
#pragma unroll
  for (int kb = 0; kb < 2; kb++) {
    unsigned a0 = cvtpk_bf16(sc[kb * 8 + 0], sc[kb * 8 + 1]);
    unsigned b0 = cvtpk_bf16(sc[kb * 8 + 2], sc[kb * 8 + 3]);
    unsigned a1 = cvtpk_bf16(sc[kb * 8 + 4], sc[kb * 8 + 5]);
    unsigned b1 = cvtpk_bf16(sc[kb * 8 + 6], sc[kb * 8 + 7]);
    i32x2 ra = __builtin_amdgcn_permlane32_swap((int)a0, (int)a1, false, false);
    i32x2 rb = __builtin_amdgcn_permlane32_swap((int)b0, (int)b1, false, false);
    union { unsigned u[4]; bf16x8 v; } pf;
    pf.u[0] = (unsigned)ra[0]; pf.u[1] = (unsigned)rb[0];
    pf.u[2] = (unsigned)ra[1]; pf.u[3] = (unsigned)rb[1];
    __builtin_amdgcn_s_setprio(1);
    o_acc = __builtin_amdgcn_mfma_f32_32x32x16_bf16(kb ? va1 : va0, pf.v, o_acc, 0, 0, 0);
    __builtin_amdgcn_s_setprio(0);
  }
}

// ---------------- Flash attention v16: ping-pong pipeline + setprio (r19 best) ----------------
__global__ __launch_bounds__(512, 4) void attn_kernel(const hbf* __restrict__ qbuf, const hbf* __restrict__ kg,
                                                      const hbf* __restrict__ vg, hbf* __restrict__ attn_t) {
  int bid = blockIdx.x;
  int xcd = bid & 7, idx = bid >> 3;       // 128 blocks per XCD
  int combo = (xcd << 1) | (idx >> 6);     // 16 (bt,h) combos; 2 per XCD
  int bt = combo >> 3, h = combo & 7;
  int s0 = (idx & 63) << 6;                // 64 q-blocks of 64
  int tid = threadIdx.x, lane = tid & 63, w = tid >> 6;
  int wq = w & 1, wt = w >> 1;
  int l31 = lane & 31, hi = lane >> 5;
  const int loff = (l31 << 4) + (hi << 3);
  int qrow = s0 + wq * 32 + l31;
  bf16x8 qf0 = *(const bf16x8*)&qbuf[((size_t)bt * S_ + qrow) * C_ + h * HD + hi * 8];
  bf16x8 qf1 = *(const bf16x8*)&qbuf[((size_t)bt * S_ + qrow) * C_ + h * HD + 16 + hi * 8];
  f32x16 o_acc = {0.f,0.f,0.f,0.f,0.f,0.f,0.f,0.f,0.f,0.f,0.f,0.f,0.f,0.f,0.f,0.f};
  const f32x16 z16 = o_acc;
  float l_run = 0.f;
  const int tq0 = wt << 10;
  const hbf* kq = kg + ((size_t)(bt * NH + h) * (S_ >> 5) + (tq0 >> 5)) * 1024;
  const hbf* vq = vg + ((size_t)(bt * NH + h) * (S_ >> 4) + (tq0 >> 4)) * 512;
  // ---- prologue: scores(0); carry kaB = K[1], vaA = V[0] ----
  bf16x8 kaB0 = *(const bf16x8*)(kq + loff);
  bf16x8 kaB1 = *(const bf16x8*)(kq + loff + 512);
  f32x16 scA = __builtin_amdgcn_mfma_f32_32x32x16_bf16(kaB0, qf0, z16, 0, 0, 0);
  scA = __builtin_amdgcn_mfma_f32_32x32x16_bf16(kaB1, qf1, scA, 0, 0, 0);   // scores(0)
  kaB0 = *(const bf16x8*)(kq + loff + 1024);                                 // K[1]
  kaB1 = *(const bf16x8*)(kq + loff + 1536);
  bf16x8 vaA0 = *(const bf16x8*)(vq + loff);                                 // V[0]
  bf16x8 vaA1 = *(const bf16x8*)(vq + loff + 512);
  kq += 2048;   // -> K[2] base
  vq += 1024;   // -> V[1] base
  // ---- steady state: j = 0..14, tiles (2j, 2j+1) ----
  for (int j = 0; j < 15; ++j) {
    bf16x8 vaB0 = *(const bf16x8*)(vq + loff);            // V[2j+1]
    bf16x8 vaB1 = *(const bf16x8*)(vq + loff + 512);
    bf16x8 knA0 = *(const bf16x8*)(kq + loff);            // K[2j+2]
    bf16x8 knA1 = *(const bf16x8*)(kq + loff + 512);
    __builtin_amdgcn_s_setprio(1);
    f32x16 scB = __builtin_amdgcn_mfma_f32_32x32x16_bf16(kaB0, qf0, z16, 0, 0, 0);
    scB = __builtin_amdgcn_mfma_f32_32x32x16_bf16(kaB1, qf1, scB, 0, 0, 0);  // scores(2j+1)
    __builtin_amdgcn_s_setprio(0);
    kaB0 = *(const bf16x8*)(kq + loff + 1024);            // K[2j+3] (reload in place)
    kaB1 = *(const bf16x8*)(kq + loff + 1536);
    softmax_pv(scA, vaA0, vaA1, o_acc, l_run);            // tile 2j
    vaA0 = *(const bf16x8*)(vq + loff + 1024);            // V[2j+2] (reload in place)
    vaA1 = *(const bf16x8*)(vq + loff + 1536);
    __builtin_amdgcn_s_setprio(1);
    scA = __builtin_amdgcn_mfma_f32_32x32x16_bf16(knA0, qf0, z16, 0, 0, 0);
    scA = __builtin_amdgcn_mfma_f32_32x32x16_bf16(knA1, qf1, scA, 0, 0, 0);  // scores(2j+2)
    __builtin_amdgcn_s_setprio(0);
    softmax_pv(scB, vaB0, vaB1, o_acc, l_run);            // tile 2j+1
    kq += 2048; vq += 2048;
  }
  // ---- epilogue: tiles 30, 31 ----
  {
    bf16x8 vaB0 = *(const bf16x8*)(vq + loff);
    bf16x8 vaB1 = *(const bf16x8*)(vq + loff + 512);
    f32x16 scB = __builtin_amdgcn_mfma_f32_32x32x16_bf16(kaB0, qf0, z16, 0, 0, 0);
    scB = __builtin_amdgcn_mfma_f32_32x32x16_bf16(kaB1, qf1, scB, 0, 0, 0);  // scores(31)
    softmax_pv(scA, vaA0, vaA1, o_acc, l_run);            // tile 30
    softmax_pv(scB, vaB0, vaB1, o_acc, l_run);            // tile 31
  }
  // combine the 4 t-quarter partials (pure sums under fixed-max softmax)
  __shared__ f32x16 ored[6 * 64];
  __shared__ float lred[8 * 64];
  __syncthreads();
  lred[(w << 6) + lane] = l_run;
  if (wt > 0) ored[((w - 2) << 6) + lane] = o_acc;
  __syncthreads();
  if (wt == 0) {
    float l_tot = 0.f;
#pragma unroll
    for (int k = 0; k < 4; k++) {
      int wp = wq + 2 * k;
      l_tot += lred[(wp << 6) + l31] + lred[(wp << 6) + 32 + l31];
    }
    f32x16 o = o_acc;
#pragma unroll
    for (int k = 0; k < 3; k++) {
      f32x16 t2 = ored[((wq + 2 * k) << 6) + lane];
#pragma unroll
      for (int i = 0; i < 16; i++) o[i] += t2[i];
    }
    float inv_l = 1.0f / l_tot;
#pragma unroll
    for (int c2 = 0; c2 < 4; c2++) {
      alignas(8) hbf tmp[4];
#pragma unroll
      for (int r = 0; r < 4; r++) tmp[r] = __float2bfloat16(o[c2 * 4 + r] * inv_l);
      *(uint2*)&attn_t[((size_t)bt * S_ + qrow) * C_ + h * HD + c2 * 8 + hi * 4] = *(uint2*)tmp;
    }
  }
}

// ---------------- Proj GEMM v2: LDS-free, fragment-major W, coalesced f32 out ----------------
__global__ __launch_bounds__(256) void proj_gemm(const hbf* __restrict__ attn_t, const hbf* __restrict__ wf,
                                                 const float* __restrict__ bias, const float* __restrict__ x,
                                                 float* __restrict__ out) {
  int bt = blockIdx.z;
  int s_blk = blockIdx.x * 64;
  int o_blk = blockIdx.y * 64;
  int tid = threadIdx.x, lane = tid & 63, w = tid >> 6;
  int wo = w & 1, ws = w >> 1;
  int l31 = lane & 31, hi = lane >> 5;
  const int loff = l31 * 16 + hi * 8;
  int o0 = o_blk + wo * 32;
  int s0 = s_blk + ws * 32;
  const hbf* ap = wf + (size_t)(o0 >> 5) * 8192;               // fragment-major W chunk
  const hbf* bp = attn_t + ((size_t)bt * S_ + s0 + l31) * C_ + hi * 8;  // row s = s0+l31
  f32x16 acc = {0.f,0.f,0.f,0.f,0.f,0.f,0.f,0.f,0.f,0.f,0.f,0.f,0.f,0.f,0.f,0.f};
#pragma unroll 4
  for (int ks = 0; ks < 16; ++ks) {
    bf16x8 af = *(const bf16x8*)(ap + ks * 512 + loff);
    bf16x8 bf_ = *(const bf16x8*)(bp + ks * 16);
    acc = __builtin_amdgcn_mfma_f32_32x32x16_bf16(af, bf_, acc, 0, 0, 0);
  }
  int s = s0 + l31;
#pragma unroll
  for (int r = 0; r < 16; r++) {
    int o = o0 + (r & 3) + 8 * (r >> 2) + 4 * hi;
    size_t idx = ((size_t)bt * C_ + o) * S_ + s;
    out[idx] = acc[r] + bias[o] + x[idx];
  }
}

extern "C" void kernel_launch(void* const* d_in, const int* in_sizes, int n_in,
                              void* d_out, int out_size, void* d_ws, size_t ws_size,
                              hipStream_t stream) {
  const float* x = (const float*)d_in[0];
  const float* gn_w = (const float*)d_in[1];
  const float* gn_b = (const float*)d_in[2];
  const float* qkv_w = (const float*)d_in[3];
  const float* qkv_b = (const float*)d_in[4];
  const float* proj_w = (const float*)d_in[5];
  const float* proj_b = (const float*)d_in[6];
  float* out = (float*)d_out;

  hbf* qkv_wf = (hbf*)d_ws;                                     // 768*256 (fragment-major)
  hbf* proj_wf = qkv_wf + 768 * 256;                            // 256*256 (fragment-major)
  hbf* xn = proj_wf + 256 * 256;                                // B*S*C (fragment-major)
  hbf* qbuf = xn + (size_t)B_ * S_ * C_;                        // B*S*C (q, scaled, [s][c])
  hbf* kg = qbuf + (size_t)B_ * S_ * C_;                        // B*NH*(S/32)*2*[32][16]
  hbf* vg = kg + (size_t)B_ * S_ * C_;                          // B*NH*(S/16)*32*16
  hbf* attn_t = vg + (size_t)B_ * S_ * C_;                      // B*S*C
  float* stats = (float*)(attn_t + (size_t)B_ * S_ * C_);       // 64*8*2 f32 partials
  int* cnt = (int*)(stats + 64 * 8 * 2);                        // 64 arrival counters

  hipMemsetAsync(cnt, 0, 64 * sizeof(int), stream);             // reset barrier counters each call
  dim3 blk(256);
  gnw_fused<<<640, blk, 0, stream>>>(qkv_w, proj_w, x, gn_w, gn_b, qkv_wf, proj_wf, stats, cnt, xn);
  qkv_gemm<<<dim3(32, 6, 2), dim3(512), 0, stream>>>(xn, qkv_wf, qkv_b, qbuf, kg, vg);
  attn_kernel<<<dim3(1024), dim3(512), 0, stream>>>(qbuf, kg, vg, attn_t);
  proj_gemm<<<dim3(64, 4, 2), blk, 0, stream>>>(attn_t, proj_wf, proj_b, x, out);
}

// Round 21
// 79.116 us; speedup vs baseline: 2.0216x; 2.0216x over previous
//
#include <hip/hip_runtime.h>
#include <hip/hip_bf16.h>

#define B_ 2
#define C_ 256
#define S_ 4096
#define NH 8
#define HD 32
#define EPSV 1e-5f
// QSCALE * log2(e): scores computed in log2 units so softmax uses exp2
#define QSC2 0.25503487942324256f

typedef __bf16 bf16_t;
typedef bf16_t bf16x8 __attribute__((ext_vector_type(8)));
typedef float f32x4 __attribute__((ext_vector_type(4)));
typedef float f32x16 __attribute__((ext_vector_type(16)));
typedef int i32x2 __attribute__((ext_vector_type(2)));
typedef __hip_bfloat16 hbf;

__device__ inline unsigned cvtpk_bf16(float a, float b) {
  unsigned r;
  asm("v_cvt_pk_bf16_f32 %0, %1, %2" : "=v"(r) : "v"(a), "v"(b));
  return r;
}

// raw hardware exp2 (v_exp_f32): scores are tiny, no range handling needed
#if __has_builtin(__builtin_amdgcn_exp2f)
#define EXP2R(x) __builtin_amdgcn_exp2f(x)
#else
#define EXP2R(x) exp2f(x)
#endif

// ---------------- gn_all: groupnorm (redundant per-block stats, NO cross-block sync) + weight conv ----------------
// blocks [0,256): gn. bg = blk>>2 owns group (b,g); quarter = blk&3. EACH block computes the FULL
// group's stats (identical data, identical order -> bitwise-identical mean/rstd across siblings;
// 4x read amplification absorbed by L2/L3), then applies+stores its own quarter (1024 s rows).
// blocks [256,288): weight conversion to fragment-major wf[o/32][c/16][o%32][16].
__global__ __launch_bounds__(1024) void gn_all(const float* __restrict__ x,
                                               const float* __restrict__ gn_w,
                                               const float* __restrict__ gn_b,
                                               const float* __restrict__ qkv_w,
                                               const float* __restrict__ proj_w,
                                               hbf* __restrict__ xn,
                                               hbf* __restrict__ qkv_wf, hbf* __restrict__ proj_wf) {
  int blk = blockIdx.x;
  int tid = threadIdx.x;
  if (blk >= 256) {
    // weight conversion: 32 blocks x 1024 chunks of 8 c-elems
    int i = (blk - 256) * 1024 + tid;          // 0..32767; 24576 qkv + 8192 proj
    const float* src;
    hbf* dst;
    int j;
    if (i < 24576) { src = qkv_w; dst = qkv_wf; j = i; }
    else { src = proj_w; dst = proj_wf; j = i - 24576; }
    int o = j >> 5, c8 = (j & 31) * 8;
    alignas(16) hbf tmp[8];
#pragma unroll
    for (int k = 0; k < 8; k++) tmp[k] = __float2bfloat16(src[(size_t)o * C_ + c8 + k]);
    *(uint4*)&dst[(((size_t)(o >> 5) * 16) + (c8 >> 4)) * 512 + (o & 31) * 16 + (c8 & 15)] = *(uint4*)tmp;
    return;
  }
  // ---- gn: full-group stats (redundant across the 4 sibling blocks) ----
  int bg = blk >> 2, quarter = blk & 3;
  int b = bg >> 5, g = bg & 31;
  const float* xp = x + (size_t)bg * 8 * S_;
  const float4* xp4 = (const float4*)xp;
  float sum = 0.f, sumsq = 0.f;
#pragma unroll
  for (int p = 0; p < 8; p++) {
    int i = tid + p * 1024;                    // 8192 float4s: 8 ch x 1024
    float4 v = xp4[i];
    sum += v.x + v.y + v.z + v.w;
    sumsq += v.x * v.x + v.y * v.y + v.z * v.z + v.w * v.w;
  }
#pragma unroll
  for (int off = 32; off > 0; off >>= 1) {
    sum += __shfl_down(sum, off);
    sumsq += __shfl_down(sumsq, off);
  }
  __shared__ float red[2][16];
  int wid = tid >> 6;
  if ((tid & 63) == 0) { red[0][wid] = sum; red[1][wid] = sumsq; }
  __syncthreads();
  sum = 0.f; sumsq = 0.f;
#pragma unroll
  for (int k = 0; k < 16; k++) { sum += red[0][k]; sumsq += red[1][k]; }  // fixed order: deterministic
  const float inv_n = 1.f / (8 * S_);
  float mean = sum * inv_n;
  float rstd = rsqrtf(fmaxf(sumsq * inv_n - mean * mean, 0.f) + EPSV);
  float scv[8], shv[8];
#pragma unroll
  for (int c = 0; c < 8; c++) {
    scv[c] = gn_w[g * 8 + c] * rstd;
    shv[c] = gn_b[g * 8 + c] - mean * scv[c];
  }
  // ---- apply: this block's quarter (1024 s rows, one per thread) ----
  int s = quarter * 1024 + tid;
  alignas(16) hbf tmp[8];
#pragma unroll
  for (int c = 0; c < 8; c++)
    tmp[c] = __float2bfloat16(xp[(size_t)c * S_ + s] * scv[c] + shv[c]);
  *(uint4*)&xn[(((size_t)b * (S_ >> 5) + (s >> 5)) * 16 + (g >> 1)) * 512 + (s & 31) * 16 + (g & 1) * 8] =
      *(uint4*)tmp;
}

// ---------------- QKV GEMM v2: LDS-free, fragment-major A and B ----------------
__global__ __launch_bounds__(512, 4) void qkv_gemm(const hbf* __restrict__ xn, const hbf* __restrict__ wf,
                                                   const float* __restrict__ bias,
                                                   hbf* __restrict__ qbuf, hbf* __restrict__ kg,
                                                   hbf* __restrict__ vg) {
  int bt = blockIdx.z;
  int m0 = blockIdx.x * 128;          // s-base within batch
  int n0 = blockIdx.y * 128;          // o-base
  int tid = threadIdx.x, lane = tid & 63, w = tid >> 6;
  int wq = w & 3, wo = w >> 2;
  int l31 = lane & 31, hi = lane >> 5;
  const int loff = l31 * 16 + hi * 8;
  const hbf* ap = xn + ((size_t)bt * (S_ >> 5) + (m0 >> 5) + wq) * 8192;
  int oc0 = n0 + wo * 64;
  const hbf* bp0 = wf + (size_t)(oc0 >> 5) * 8192;
  const hbf* bp1 = bp0 + 8192;
  f32x16 acc0 = {0.f,0.f,0.f,0.f,0.f,0.f,0.f,0.f,0.f,0.f,0.f,0.f,0.f,0.f,0.f,0.f};
  f32x16 acc1 = acc0;
#pragma unroll 4
  for (int ks = 0; ks < 16; ++ks) {
    bf16x8 af = *(const bf16x8*)(ap + ks * 512 + loff);
    bf16x8 b0 = *(const bf16x8*)(bp0 + ks * 512 + loff);
    bf16x8 b1 = *(const bf16x8*)(bp1 + ks * 512 + loff);
    acc0 = __builtin_amdgcn_mfma_f32_32x32x16_bf16(af, b0, acc0, 0, 0, 0);
    acc1 = __builtin_amdgcn_mfma_f32_32x32x16_bf16(af, b1, acc1, 0, 0, 0);
  }
  int s_base = m0 + wq * 32;
#pragma unroll
  for (int ct = 0; ct < 2; ++ct) {
    f32x16 a = ct ? acc1 : acc0;
    int oc = oc0 + ct * 32;           // uniform per col-tile
    int o = oc + l31;
    float bs = bias[o];
    if (oc < 256) {
#pragma unroll
      for (int r = 0; r < 16; r++) {
        int s = s_base + (r & 3) + 8 * (r >> 2) + 4 * hi;
        qbuf[((size_t)bt * S_ + s) * C_ + o] = __float2bfloat16((a[r] + bs) * QSC2);
      }
    } else if (oc < 512) {
      int hh = (oc - 256) >> 5;
      const size_t khead = (size_t)(bt * NH + hh) * (S_ >> 5);
#pragma unroll
      for (int r = 0; r < 16; r++) {
        int s = s_base + (r & 3) + 8 * (r >> 2) + 4 * hi;
        kg[(khead + (s >> 5)) * 1024 + (l31 >> 4) * 512 + (s & 31) * 16 + (l31 & 15)] =
            __float2bfloat16(a[r] + bs);
      }
    } else {
      int hh = (oc - 512) >> 5;
      const size_t vhead = (size_t)(bt * NH + hh) * (S_ >> 4);
#pragma unroll
      for (int r = 0; r < 16; r++) {
        int s = s_base + (r & 3) + 8 * (r >> 2) + 4 * hi;
        vg[(vhead + (s >> 4)) * 512 + l31 * 16 + (s & 15)] = __float2bfloat16(a[r] + bs);
      }
    }
  }
}

// softmax numerator + P relayout + PV for ONE 32-t tile (consumes sc of that tile)
// l via VALU tree (measured best split: r18 showed ones-MFMA overloads the MFMA pipe)
__device__ inline void softmax_pv(f32x16 sc, bf16x8 va0, bf16x8 va1,
                                  f32x16& o_acc, float& l_run) {
#pragma unroll
  for (int i = 0; i < 16; i++) sc[i] = EXP2R(sc[i]);
  {
    float s0a = sc[0] + sc[1], s1a = sc[2] + sc[3], s2a = sc[4] + sc[5], s3a = sc[6] + sc[7];
    float s4a = sc[8] + sc[9], s5a = sc[10] + sc[11], s6a = sc[12] + sc[13], s7a = sc[14] + sc[15];
    s0a += s1a; s2a += s3a; s4a += s5a; s6a += s7a;
    s0a += s2a; s4a += s6a;
    l_run += s0a + s4a;
  }
#pragma unroll
  for (int kb = 0; kb < 2; kb++) {
    unsigned a0 = cvtpk_bf16(sc[kb * 8 + 0], sc[kb * 8 + 1]);
    unsigned b0 = cvtpk_bf16(sc[kb * 8 + 2], sc[kb * 8 + 3]);
    unsigned a1 = cvtpk_bf16(sc[kb * 8 + 4], sc[kb * 8 + 5]);
    unsigned b1 = cvtpk_bf16(sc[kb * 8 + 6], sc[kb * 8 + 7]);
    i32x2 ra = __builtin_amdgcn_permlane32_swap((int)a0, (int)a1, false, false);
    i32x2 rb = __builtin_amdgcn_permlane32_swap((int)b0, (int)b1, false, false);
    union { unsigned u[4]; bf16x8 v; } pf;
    pf.u[0] = (unsigned)ra[0]; pf.u[1] = (unsigned)rb[0];
    pf.u[2] = (unsigned)ra[1]; pf.u[3] = (unsigned)rb[1];
    __builtin_amdgcn_s_setprio(1);
    o_acc = __builtin_amdgcn_mfma_f32_32x32x16_bf16(kb ? va1 : va0, pf.v, o_acc, 0, 0, 0);
    __builtin_amdgcn_s_setprio(0);
  }
}

// ---------------- Flash attention v16: ping-pong pipeline + setprio (r19 best) ----------------
__global__ __launch_bounds__(512, 4) void attn_kernel(const hbf* __restrict__ qbuf, const hbf* __restrict__ kg,
                                                      const hbf* __restrict__ vg, hbf* __restrict__ attn_t) {
  int bid = blockIdx.x;
  int xcd = bid & 7, idx = bid >> 3;       // 128 blocks per XCD
  int combo = (xcd << 1) | (idx >> 6);     // 16 (bt,h) combos; 2 per XCD
  int bt = combo >> 3, h = combo & 7;
  int s0 = (idx & 63) << 6;                // 64 q-blocks of 64
  int tid = threadIdx.x, lane = tid & 63, w = tid >> 6;
  int wq = w & 1, wt = w >> 1;
  int l31 = lane & 31, hi = lane >> 5;
  const int loff = (l31 << 4) + (hi << 3);
  int qrow = s0 + wq * 32 + l31;
  bf16x8 qf0 = *(const bf16x8*)&qbuf[((size_t)bt * S_ + qrow) * C_ + h * HD + hi * 8];
  bf16x8 qf1 = *(const bf16x8*)&qbuf[((size_t)bt * S_ + qrow) * C_ + h * HD + 16 + hi * 8];
  f32x16 o_acc = {0.f,0.f,0.f,0.f,0.f,0.f,0.f,0.f,0.f,0.f,0.f,0.f,0.f,0.f,0.f,0.f};
  const f32x16 z16 = o_acc;
  float l_run = 0.f;
  const int tq0 = wt << 10;
  const hbf* kq = kg + ((size_t)(bt * NH + h) * (S_ >> 5) + (tq0 >> 5)) * 1024;
  const hbf* vq = vg + ((size_t)(bt * NH + h) * (S_ >> 4) + (tq0 >> 4)) * 512;
  // ---- prologue: scores(0); carry kaB = K[1], vaA = V[0] ----
  bf16x8 kaB0 = *(const bf16x8*)(kq + loff);
  bf16x8 kaB1 = *(const bf16x8*)(kq + loff + 512);
  f32x16 scA = __builtin_amdgcn_mfma_f32_32x32x16_bf16(kaB0, qf0, z16, 0, 0, 0);
  scA = __builtin_amdgcn_mfma_f32_32x32x16_bf16(kaB1, qf1, scA, 0, 0, 0);   // scores(0)
  kaB0 = *(const bf16x8*)(kq + loff + 1024);                                 // K[1]
  kaB1 = *(const bf16x8*)(kq + loff + 1536);
  bf16x8 vaA0 = *(const bf16x8*)(vq + loff);                                 // V[0]
  bf16x8 vaA1 = *(const bf16x8*)(vq + loff + 512);
  kq += 2048;   // -> K[2] base
  vq += 1024;   // -> V[1] base
  // ---- steady state: j = 0..14, tiles (2j, 2j+1) ----
  for (int j = 0; j < 15; ++j) {
    bf16x8 vaB0 = *(const bf16x8*)(vq + loff);            // V[2j+1]
    bf16x8 vaB1 = *(const bf16x8*)(vq + loff + 512);
    bf16x8 knA0 = *(const bf16x8*)(kq + loff);            // K[2j+2]
    bf16x8 knA1 = *(const bf16x8*)(kq + loff + 512);
    __builtin_amdgcn_s_setprio(1);
    f32x16 scB = __builtin_amdgcn_mfma_f32_32x32x16_bf16(kaB0, qf0, z16, 0, 0, 0);
    scB = __builtin_amdgcn_mfma_f32_32x32x16_bf16(kaB1, qf1, scB, 0, 0, 0);  // scores(2j+1)
    __builtin_amdgcn_s_setprio(0);
    kaB0 = *(const bf16x8*)(kq + loff + 1024);            // K[2j+3] (reload in place)
    kaB1 = *(const bf16x8*)(kq + loff + 1536);
    softmax_pv(scA, vaA0, vaA1, o_acc, l_run);            // tile 2j
    vaA0 = *(const bf16x8*)(vq + loff + 1024);            // V[2j+2] (reload in place)
    vaA1 = *(const bf16x8*)(vq + loff + 1536);
    __builtin_amdgcn_s_setprio(1);
    scA = __builtin_amdgcn_mfma_f32_32x32x16_bf16(knA0, qf0, z16, 0, 0, 0);
    scA = __builtin_amdgcn_mfma_f32_32x32x16_bf16(knA1, qf1, scA, 0, 0, 0);  // scores(2j+2)
    __builtin_amdgcn_s_setprio(0);
    softmax_pv(scB, vaB0, vaB1, o_acc, l_run);            // tile 2j+1
    kq += 2048; vq += 2048;
  }
  // ---- epilogue: tiles 30, 31 ----
  {
    bf16x8 vaB0 = *(const bf16x8*)(vq + loff);
    bf16x8 vaB1 = *(const bf16x8*)(vq + loff + 512);
    f32x16 scB = __builtin_amdgcn_mfma_f32_32x32x16_bf16(kaB0, qf0, z16, 0, 0, 0);
    scB = __builtin_amdgcn_mfma_f32_32x32x16_bf16(kaB1, qf1, scB, 0, 0, 0);  // scores(31)
    softmax_pv(scA, vaA0, vaA1, o_acc, l_run);            // tile 30
    softmax_pv(scB, vaB0, vaB1, o_acc, l_run);            // tile 31
  }
  // combine the 4 t-quarter partials (pure sums under fixed-max softmax)
  __shared__ f32x16 ored[6 * 64];
  __shared__ float lred[8 * 64];
  __syncthreads();
  lred[(w << 6) + lane] = l_run;
  if (wt > 0) ored[((w - 2) << 6) + lane] = o_acc;
  __syncthreads();
  if (wt == 0) {
    float l_tot = 0.f;
#pragma unroll
    for (int k = 0; k < 4; k++) {
      int wp = wq + 2 * k;
      l_tot += lred[(wp << 6) + l31] + lred[(wp << 6) + 32 + l31];
    }
    f32x16 o = o_acc;
#pragma unroll
    for (int k = 0; k < 3; k++) {
      f32x16 t2 = ored[((wq + 2 * k) << 6) + lane];
#pragma unroll
      for (int i = 0; i < 16; i++) o[i] += t2[i];
    }
    float inv_l = 1.0f / l_tot;
#pragma unroll
    for (int c2 = 0; c2 < 4; c2++) {
      alignas(8) hbf tmp[4];
#pragma unroll
      for (int r = 0; r < 4; r++) tmp[r] = __float2bfloat16(o[c2 * 4 + r] * inv_l);
      *(uint2*)&attn_t[((size_t)bt * S_ + qrow) * C_ + h * HD + c2 * 8 + hi * 4] = *(uint2*)tmp;
    }
  }
}

// ---------------- Proj GEMM v2: LDS-free, fragment-major W, coalesced f32 out ----------------
__global__ __launch_bounds__(256) void proj_gemm(const hbf* __restrict__ attn_t, const hbf* __restrict__ wf,
                                                 const float* __restrict__ bias, const float* __restrict__ x,
                                                 float* __restrict__ out) {
  int bt = blockIdx.z;
  int s_blk = blockIdx.x * 64;
  int o_blk = blockIdx.y * 64;
  int tid = threadIdx.x, lane = tid & 63, w = tid >> 6;
  int wo = w & 1, ws = w >> 1;
  int l31 = lane & 31, hi = lane >> 5;
  const int loff = l31 * 16 + hi * 8;
  int o0 = o_blk + wo * 32;
  int s0 = s_blk + ws * 32;
  const hbf* ap = wf + (size_t)(o0 >> 5) * 8192;               // fragment-major W chunk
  const hbf* bp = attn_t + ((size_t)bt * S_ + s0 + l31) * C_ + hi * 8;  // row s = s0+l31
  f32x16 acc = {0.f,0.f,0.f,0.f,0.f,0.f,0.f,0.f,0.f,0.f,0.f,0.f,0.f,0.f,0.f,0.f};
#pragma unroll 4
  for (int ks = 0; ks < 16; ++ks) {
    bf16x8 af = *(const bf16x8*)(ap + ks * 512 + loff);
    bf16x8 bf_ = *(const bf16x8*)(bp + ks * 16);
    acc = __builtin_amdgcn_mfma_f32_32x32x16_bf16(af, bf_, acc, 0, 0, 0);
  }
  int s = s0 + l31;
#pragma unroll
  for (int r = 0; r < 16; r++) {
    int o = o0 + (r & 3) + 8 * (r >> 2) + 4 * hi;
    size_t idx = ((size_t)bt * C_ + o) * S_ + s;
    out[idx] = acc[r] + bias[o] + x[idx];
  }
}

extern "C" void kernel_launch(void* const* d_in, const int* in_sizes, int n_in,
                              void* d_out, int out_size, void* d_ws, size_t ws_size,
                              hipStream_t stream) {
  const float* x = (const float*)d_in[0];
  const float* gn_w = (const float*)d_in[1];
  const float* gn_b = (const float*)d_in[2];
  const float* qkv_w = (const float*)d_in[3];
  const float* qkv_b = (const float*)d_in[4];
  const float* proj_w = (const float*)d_in[5];
  const float* proj_b = (const float*)d_in[6];
  float* out = (float*)d_out;

  hbf* qkv_wf = (hbf*)d_ws;                                     // 768*256 (fragment-major)
  hbf* proj_wf = qkv_wf + 768 * 256;                            // 256*256 (fragment-major)
  hbf* xn = proj_wf + 256 * 256;                                // B*S*C (fragment-major)
  hbf* qbuf = xn + (size_t)B_ * S_ * C_;                        // B*S*C (q, scaled, [s][c])
  hbf* kg = qbuf + (size_t)B_ * S_ * C_;                        // B*NH*(S/32)*2*[32][16]
  hbf* vg = kg + (size_t)B_ * S_ * C_;                          // B*NH*(S/16)*32*16
  hbf* attn_t = vg + (size_t)B_ * S_ * C_;                      // B*S*C

  gn_all<<<288, dim3(1024), 0, stream>>>(x, gn_w, gn_b, qkv_w, proj_w, xn, qkv_wf, proj_wf);
  qkv_gemm<<<dim3(32, 6, 2), dim3(512), 0, stream>>>(xn, qkv_wf, qkv_b, qbuf, kg, vg);
  attn_kernel<<<dim3(1024), dim3(512), 0, stream>>>(qbuf, kg, vg, attn_t);
  proj_gemm<<<dim3(64, 4, 2), dim3(256), 0, stream>>>(attn_t, proj_wf, proj_b, x, out);
}